// Round 13
// baseline (63.716 us; speedup 1.0000x reference)
//
#include <hip/hip_runtime.h>
#include <hip/hip_bf16.h>

// ---- problem constants ----
#define NBATCH   16
#define SIGLEN   240000
#define FRAMES   1197                 // (240000-800)/200 + 1
#define M_TOTAL  (NBATCH * FRAMES)    // 19152 = 1197 * 16 exactly
#define K_TOTAL  800
#define NBINS    401
#define NOUT     (2 * NBINS)          // 802, interleaved re/im
#define FSTEP    200

// ---- GEMM geometry ----
#define KPAD  832                     // K padded to 26*32 (B cols 800..831 zero)
#define NTK   26                      // K-steps of 32
#define GBN   64                      // N cols per block (B panel rows)
#define GMB   1024                    // M rows per block (8 waves x 128)
#define GNT   13                      // ceil(802/64)
#define GMT   19                      // ceil(19152/1024)
#define GNWG  (GNT * GMT)             // 247 blocks -> 1/CU
#define BSTR  840                     // LDS row stride bf16
#define NRG   1197                    // row-groups of 16 (exact)

#define SIG_ELEMS  ((size_t)NBATCH * SIGLEN)          // 3,840,000 bf16
#define B_WS_ELEMS ((size_t)(GNT * GBN) * KPAD)       // 692,224 bf16
#define APK_ELEMS  ((size_t)NRG * NTK * 64 * 8)       // 15,937,536 bf16 (~31.9MB)
#define WS_TIER2   ((SIG_ELEMS + B_WS_ELEMS) * 2)                 // ~9.07 MB
#define WS_TIER1   ((SIG_ELEMS + B_WS_ELEMS + APK_ELEMS) * 2)     // ~40.9 MB

#define PREP_SIG_BLOCKS 1875          // SIG_ELEMS/8/256
#define PREP_B_BLOCKS   338           // 832 rows * 104 chunks / 256
#define PACK_TOTAL (NRG * NTK * 64)   // 1,991,808 threads
#define PACK_BLOCKS ((PACK_TOTAL + 255) / 256)

typedef float  f32x4  __attribute__((ext_vector_type(4)));
typedef __bf16 bf16x8 __attribute__((ext_vector_type(8)));

static __device__ __forceinline__ unsigned f2bf_pair(float lo, float hi) {
    union { float f; unsigned u; } a, b;
    a.f = lo; b.f = hi;
    unsigned ua = (a.u + 0x7fffu + ((a.u >> 16) & 1u)) >> 16;
    unsigned ub = (b.u + 0x7fffu + ((b.u >> 16) & 1u)) >> 16;
    return ua | (ub << 16);
}

// ============================================================================
// fused prep: blocks [0,1875) convert signal f32->bf16;
// blocks [1875,2213) build windowed interleaved-DFT bf16 rows, K-pad to 832
// ============================================================================
__global__ __launch_bounds__(256) void prep_all(
    const float* __restrict__ sig, const float* __restrict__ wnd,
    const float* __restrict__ dcos, const float* __restrict__ dsin,
    ushort* __restrict__ sbf, ushort* __restrict__ B)
{
    const int blk = blockIdx.x;
    if (blk < PREP_SIG_BLOCKS) {
        size_t i8 = ((size_t)blk * 256 + threadIdx.x) * 8;
        const float4 s0 = *(const float4*)(sig + i8);
        const float4 s1 = *(const float4*)(sig + i8 + 4);
        uint4 p;
        p.x = f2bf_pair(s0.x, s0.y);
        p.y = f2bf_pair(s0.z, s0.w);
        p.z = f2bf_pair(s1.x, s1.y);
        p.w = f2bf_pair(s1.z, s1.w);
        *(uint4*)(sbf + i8) = p;
    } else {
        int idx = (blk - PREP_SIG_BLOCKS) * 256 + threadIdx.x;  // < 832*104
        int j  = idx / 104;
        int c8 = (idx - j * 104) * 8;
        uint4 p;
        if (j < NOUT && c8 < K_TOTAL) {
            const float* src = ((j & 1) ? dsin : dcos) + (size_t)(j >> 1) * K_TOTAL + c8;
            const float4 s0 = *(const float4*)(src);
            const float4 s1 = *(const float4*)(src + 4);
            const float4 w0 = *(const float4*)(wnd + c8);
            const float4 w1 = *(const float4*)(wnd + c8 + 4);
            p.x = f2bf_pair(s0.x * w0.x, s0.y * w0.y);
            p.y = f2bf_pair(s0.z * w0.z, s0.w * w0.w);
            p.z = f2bf_pair(s1.x * w1.x, s1.y * w1.y);
            p.w = f2bf_pair(s1.z * w1.z, s1.w * w1.w);
        } else {
            p = make_uint4(0u, 0u, 0u, 0u);
        }
        *(uint4*)(B + (size_t)j * KPAD + c8) = p;
    }
}

// ============================================================================
// pack A into MFMA fragment order: A_pk[(rowgrp*26 + kk)*64 + lane] (16B each)
//   lane = lr + 16*lg; element = windowed-frame row (rowgrp*16+lr),
//   cols kk*32 + lg*8 .. +8  (window folded into B, so raw signal slice).
// Scattered read happens ONCE here; GEMM A-loads become 1KB coalesced.
// Write side: consecutive tid -> consecutive lane -> coalesced 1KB/wave.
// ============================================================================
__global__ __launch_bounds__(256) void prep_pack(
    const ushort* __restrict__ sbf, ushort* __restrict__ Apk)
{
    int idx = blockIdx.x * 256 + threadIdx.x;
    if (idx >= PACK_TOTAL) return;
    const int lane   = idx & 63;
    const int kk     = (idx >> 6) % NTK;
    const int rowgrp = idx / (64 * NTK);
    const int row = rowgrp * 16 + (lane & 15);
    const int bb  = row / FRAMES, ff = row - bb * FRAMES;
    // kk=25 tail: cols 800..831 overread past frame/batch end -> lands in
    // Bws region at worst (finite bf16); multiplied by zero B cols -> 0.
    const ushort* src = sbf + (size_t)bb * SIGLEN + ff * FSTEP + kk * 32 + (lane >> 4) * 8;
    *(uint4*)(Apk + (size_t)idx * 8) = *(const uint4*)src;
}

// ============================================================================
// GEMM tier1: C[19152 x 802] = frames * Bw^T, packed-A edition.
// R8 structure (247 blocks, 512 thr, 8 waves x 128x64, B panel 64x832 in LDS,
// 26 K-steps, no K-loop barriers, depth-2 ping-pong) but A loads are fully
// coalesced aligned 1KB wave loads from A_pk (16 lines, zero straddle).
// ============================================================================
__global__ __launch_bounds__(512, 2) void stft_gemm_pk(
    const ushort* __restrict__ Apk, const ushort* __restrict__ Bw,
    float* __restrict__ out)
{
    __shared__ ushort Bs[GBN * BSTR];   // 107,520 B -> 1 block/CU

    const int tid  = threadIdx.x;

    // XCD-chunked bijective swizzle (m204): nwg=247, q=30, r=7; ntile fastest.
    const int orig = blockIdx.x;
    const int xcd  = orig & 7;
    const int idx  = orig >> 3;
    const int lbid = (xcd < 7 ? xcd * 31 : 217 + (xcd - 7) * 30) + idx;

    const int ntile = lbid % GNT;
    const int mblk  = lbid / GNT;
    const int j0    = ntile * GBN;
    const int m0    = mblk * GMB;

    const int wave = tid >> 6;
    const int lane = tid & 63;
    const int lr   = lane & 15;
    const int lg   = lane >> 4;
    const int mrow = m0 + wave * 128;

    // per-i-frag packed row-group bases (elems); lane adds lane*8
    const int g0 = (m0 >> 4) + wave * 8;
    size_t aBase[8];
    #pragma unroll
    for (int i = 0; i < 8; ++i) {
        int g = g0 + i;
        if (g >= NRG) g = NRG - 1;      // tail mblk: dup rowgrp, never stored
        aBase[i] = (size_t)g * (NTK * 512) + lane * 8;
    }

    f32x4 acc[8][4];
    #pragma unroll
    for (int i = 0; i < 8; ++i)
        #pragma unroll
        for (int jj = 0; jj < 4; ++jj)
            acc[i][jj] = (f32x4){0.f, 0.f, 0.f, 0.f};

#define LOADA(A_, step) do {                                        \
        _Pragma("unroll")                                           \
        for (int i = 0; i < 8; ++i)                                 \
            A_[i] = *(const bf16x8*)(Apk + aBase[i] + (step) * 512);\
    } while (0)

#define LOADB(B_, step) do {                                        \
        const int kofs_ = (step) * 32;                              \
        _Pragma("unroll")                                           \
        for (int jj = 0; jj < 4; ++jj)                              \
            B_[jj] = *(const bf16x8*)&Bs[jj * (16 * BSTR) + lr * BSTR + lg * 8 + kofs_]; \
    } while (0)

#define MM(A_, B_) do {                                             \
        __builtin_amdgcn_s_setprio(1);                              \
        _Pragma("unroll")                                           \
        for (int i = 0; i < 8; ++i)                                 \
            _Pragma("unroll")                                       \
            for (int jj = 0; jj < 4; ++jj)                          \
                acc[i][jj] = __builtin_amdgcn_mfma_f32_16x16x32_bf16( \
                    A_[i], B_[jj], acc[i][jj], 0, 0, 0);            \
        __builtin_amdgcn_s_setprio(0);                              \
    } while (0)

    bf16x8 aX[8], aY[8], bX[4], bY[4];

    LOADA(aX, 0);
    LOADA(aY, 1);

    // ---- stage B panel: 64 rows x 832 cols -> LDS [64][840] ----
    #pragma unroll
    for (int it = 0; it < 13; ++it) {
        int c   = tid + 512 * it;
        int row = c / 104;
        int col = (c - row * 104) * 8;
        *(uint4*)&Bs[row * BSTR + col] =
            *(const uint4*)(Bw + (size_t)(j0 + row) * KPAD + col);
    }
    __syncthreads();   // only barrier in the kernel

    LOADB(bX, 0);
    LOADB(bY, 1);

    #pragma unroll 1
    for (int t = 0; t < NTK - 2; t += 2) {
        MM(aX, bX);
        LOADA(aX, t + 2);
        LOADB(bX, t + 2);
        MM(aY, bY);
        LOADA(aY, t + 3);
        LOADB(bY, t + 3);
    }
    MM(aX, bX);   // step 24
    MM(aY, bY);   // step 25

#undef LOADA
#undef LOADB
#undef MM

    // epilogue: C/D layout col=lane&15, row=4*(lane>>4)+reg
    #pragma unroll
    for (int i = 0; i < 8; ++i) {
        #pragma unroll
        for (int jj = 0; jj < 4; ++jj) {
            int col = j0 + jj * 16 + lr;
            if (col >= NOUT) continue;
            #pragma unroll
            for (int r = 0; r < 4; ++r) {
                int row = mrow + i * 16 + lg * 4 + r;
                if (row < M_TOTAL)
                    out[(size_t)row * NOUT + col] = acc[i][jj][r];
            }
        }
    }
}

// ============================================================================
// GEMM tier2 (R12 kernel): direct-signal A, 16 waves x 64x64, no packing
// ============================================================================
__global__ __launch_bounds__(1024, 4) void stft_gemm_bp5(
    const ushort* __restrict__ sigbf, const ushort* __restrict__ Bw,
    float* __restrict__ out)
{
    __shared__ ushort Bs[GBN * BSTR];

    const int tid  = threadIdx.x;
    const int orig = blockIdx.x;
    const int xcd  = orig & 7;
    const int idx  = orig >> 3;
    const int lbid = (xcd < 7 ? xcd * 31 : 217 + (xcd - 7) * 30) + idx;

    const int ntile = lbid % GNT;
    const int mblk  = lbid / GNT;
    const int j0    = ntile * GBN;
    const int m0    = mblk * GMB;

    const int wave = tid >> 6;
    const int lane = tid & 63;
    const int lr   = lane & 15;
    const int lg   = lane >> 4;
    const int mrow = m0 + wave * 64;

    unsigned aOfs[4];
    #pragma unroll
    for (int i = 0; i < 4; ++i) {
        int row = mrow + i * 16 + lr;
        if (row >= M_TOTAL) row = M_TOTAL - 1;
        int bb = row / FRAMES, ff = row - bb * FRAMES;
        aOfs[i] = (unsigned)(bb * SIGLEN + ff * FSTEP + lg * 8);
    }
    const int bBase = lr * BSTR + lg * 8;

    f32x4 acc[4][4];
    #pragma unroll
    for (int i = 0; i < 4; ++i)
        #pragma unroll
        for (int jj = 0; jj < 4; ++jj)
            acc[i][jj] = (f32x4){0.f, 0.f, 0.f, 0.f};

#define LOADA(A_, step) do {                                        \
        const int kofs_ = (step) * 32;                              \
        _Pragma("unroll")                                           \
        for (int i = 0; i < 4; ++i)                                 \
            A_[i] = *(const bf16x8*)(sigbf + aOfs[i] + kofs_);      \
    } while (0)

#define LOADB(B_, step) do {                                        \
        const int kofs_ = (step) * 32;                              \
        _Pragma("unroll")                                           \
        for (int jj = 0; jj < 4; ++jj)                              \
            B_[jj] = *(const bf16x8*)&Bs[jj * (16 * BSTR) + bBase + kofs_]; \
    } while (0)

#define MM(A_, B_) do {                                             \
        __builtin_amdgcn_s_setprio(1);                              \
        _Pragma("unroll")                                           \
        for (int i = 0; i < 4; ++i)                                 \
            _Pragma("unroll")                                       \
            for (int jj = 0; jj < 4; ++jj)                          \
                acc[i][jj] = __builtin_amdgcn_mfma_f32_16x16x32_bf16( \
                    A_[i], B_[jj], acc[i][jj], 0, 0, 0);            \
        __builtin_amdgcn_s_setprio(0);                              \
    } while (0)

    bf16x8 aX[4], aY[4], bX[4];

    LOADA(aX, 0);
    LOADA(aY, 1);

    #pragma unroll
    for (int it = 0; it < 6; ++it) {
        int c   = tid + 1024 * it;
        int row = c / 104;
        int col = (c - row * 104) * 8;
        *(uint4*)&Bs[row * BSTR + col] =
            *(const uint4*)(Bw + (size_t)(j0 + row) * KPAD + col);
    }
    if (tid < 512) {
        int c   = tid + 6144;
        int row = c / 104;
        int col = (c - row * 104) * 8;
        *(uint4*)&Bs[row * BSTR + col] =
            *(const uint4*)(Bw + (size_t)(j0 + row) * KPAD + col);
    }
    __syncthreads();

    #pragma unroll 1
    for (int t = 0; t < NTK - 2; t += 2) {
        LOADB(bX, t);
        MM(aX, bX);
        LOADA(aX, t + 2);
        LOADB(bX, t + 1);
        MM(aY, bX);
        LOADA(aY, t + 3);
    }
    LOADB(bX, 24); MM(aX, bX);
    LOADB(bX, 25); MM(aY, bX);

#undef LOADA
#undef LOADB
#undef MM

    #pragma unroll
    for (int i = 0; i < 4; ++i) {
        #pragma unroll
        for (int jj = 0; jj < 4; ++jj) {
            int col = j0 + jj * 16 + lr;
            if (col >= NOUT) continue;
            #pragma unroll
            for (int r = 0; r < 4; ++r) {
                int row = mrow + i * 16 + lg * 4 + r;
                if (row < M_TOTAL)
                    out[(size_t)row * NOUT + col] = acc[i][jj][r];
            }
        }
    }
}

// ============================================================================
// fallback (no workspace): in-kernel gather+window+convert
// ============================================================================
#define BM 128
#define BN 128
#define BK 32
#define NTILES_N 7
#define NTILES_M 150
#define NWG (NTILES_M * NTILES_N)
#define LDSS 40
__global__ __launch_bounds__(256) void stft_gemm_fb(
    const float* __restrict__ sig, const float* __restrict__ wnd,
    const float* __restrict__ dcos, const float* __restrict__ dsin,
    float* __restrict__ out)
{
    __shared__ ushort As[BM * LDSS];
    __shared__ ushort Bs[BN * LDSS];
    __shared__ int rowBase[BM];

    const int tid = threadIdx.x;
    const int bid = blockIdx.x;
    const int mt  = bid / NTILES_N;
    const int nt  = bid - mt * NTILES_N;
    const int m0  = mt * BM;
    const int j0  = nt * BN;

    if (tid < BM) {
        int m = m0 + tid;
        int v = -1;
        if (m < M_TOTAL) {
            int b  = m / FRAMES;
            int fl = m - b * FRAMES;
            v = b * SIGLEN + fl * FSTEP;
        }
        rowBase[tid] = v;
    }

    const int rS = tid >> 1;
    const int hS = tid & 1;

    const float* bRow = nullptr;
    {
        int j = j0 + rS;
        if (j < NOUT) {
            const float* srcm = (j & 1) ? dsin : dcos;
            bRow = srcm + (size_t)(j >> 1) * K_TOTAL;
        }
    }

    const int lane = tid & 63;
    const int wave = tid >> 6;
    const int wm   = wave >> 1;
    const int wn   = wave & 1;
    const int lr   = lane & 15;
    const int lg   = lane >> 4;

    f32x4 acc[4][4];
    #pragma unroll
    for (int i = 0; i < 4; ++i)
        #pragma unroll
        for (int jj = 0; jj < 4; ++jj)
            acc[i][jj] = (f32x4){0.f, 0.f, 0.f, 0.f};

    __syncthreads();

    for (int k0 = 0; k0 < K_TOTAL; k0 += BK) {
        {
            int base = rowBase[rS];
            float4 f0, f1, f2, f3;
            if (base >= 0) {
                const float4* sp = (const float4*)(sig + base + k0 + hS * 16);
                f0 = sp[0]; f1 = sp[1]; f2 = sp[2]; f3 = sp[3];
            } else {
                f0 = make_float4(0.f,0.f,0.f,0.f); f1 = f0; f2 = f0; f3 = f0;
            }
            const float4* wp = (const float4*)(wnd + k0 + hS * 16);
            float4 w0 = wp[0], w1 = wp[1], w2 = wp[2], w3 = wp[3];
            uint4 p0, p1;
            p0.x = f2bf_pair(f0.x * w0.x, f0.y * w0.y);
            p0.y = f2bf_pair(f0.z * w0.z, f0.w * w0.w);
            p0.z = f2bf_pair(f1.x * w1.x, f1.y * w1.y);
            p0.w = f2bf_pair(f1.z * w1.z, f1.w * w1.w);
            p1.x = f2bf_pair(f2.x * w2.x, f2.y * w2.y);
            p1.y = f2bf_pair(f2.z * w2.z, f2.w * w2.w);
            p1.z = f2bf_pair(f3.x * w3.x, f3.y * w3.y);
            p1.w = f2bf_pair(f3.z * w3.z, f3.w * w3.w);
            uint4* dst = (uint4*)&As[rS * LDSS + hS * 16];
            dst[0] = p0; dst[1] = p1;
        }
        {
            uint4 p0, p1;
            if (bRow) {
                const float4* sp = (const float4*)(bRow + k0 + hS * 16);
                float4 f0 = sp[0], f1 = sp[1], f2 = sp[2], f3 = sp[3];
                p0.x = f2bf_pair(f0.x, f0.y);
                p0.y = f2bf_pair(f0.z, f0.w);
                p0.z = f2bf_pair(f1.x, f1.y);
                p0.w = f2bf_pair(f1.z, f1.w);
                p1.x = f2bf_pair(f2.x, f2.y);
                p1.y = f2bf_pair(f2.z, f2.w);
                p1.z = f2bf_pair(f3.x, f3.y);
                p1.w = f2bf_pair(f3.z, f3.w);
            } else {
                p0 = make_uint4(0u,0u,0u,0u); p1 = p0;
            }
            uint4* dst = (uint4*)&Bs[rS * LDSS + hS * 16];
            dst[0] = p0; dst[1] = p1;
        }
        __syncthreads();

        bf16x8 a[4], b[4];
        #pragma unroll
        for (int i = 0; i < 4; ++i)
            a[i] = *(const bf16x8*)&As[(wm * 64 + i * 16 + lr) * LDSS + lg * 8];
        #pragma unroll
        for (int i = 0; i < 4; ++i)
            b[i] = *(const bf16x8*)&Bs[(wn * 64 + i * 16 + lr) * LDSS + lg * 8];
        #pragma unroll
        for (int i = 0; i < 4; ++i)
            #pragma unroll
            for (int jj = 0; jj < 4; ++jj)
                acc[i][jj] = __builtin_amdgcn_mfma_f32_16x16x32_bf16(a[i], b[jj], acc[i][jj], 0, 0, 0);

        __syncthreads();
    }

    const int mb = m0 + wm * 64;
    const int jb = j0 + wn * 64;
    #pragma unroll
    for (int i = 0; i < 4; ++i) {
        #pragma unroll
        for (int jj = 0; jj < 4; ++jj) {
            int col = jb + jj * 16 + lr;
            if (col >= NOUT) continue;
            #pragma unroll
            for (int r = 0; r < 4; ++r) {
                int row = mb + i * 16 + lg * 4 + r;
                if (row < M_TOTAL)
                    out[(size_t)row * NOUT + col] = acc[i][jj][r];
            }
        }
    }
}

extern "C" void kernel_launch(void* const* d_in, const int* in_sizes, int n_in,
                              void* d_out, int out_size, void* d_ws, size_t ws_size,
                              hipStream_t stream) {
    const float* sig  = (const float*)d_in[0];
    const float* wnd  = (const float*)d_in[1];
    const float* dcos = (const float*)d_in[2];
    const float* dsin = (const float*)d_in[3];
    float* out = (float*)d_out;

    if (ws_size >= WS_TIER1 && d_ws != nullptr) {
        ushort* sbf = (ushort*)d_ws;
        ushort* Bws = sbf + SIG_ELEMS;
        ushort* Apk = Bws + B_WS_ELEMS;
        prep_all<<<dim3(PREP_SIG_BLOCKS + PREP_B_BLOCKS), dim3(256), 0, stream>>>(
            sig, wnd, dcos, dsin, sbf, Bws);
        prep_pack<<<dim3(PACK_BLOCKS), dim3(256), 0, stream>>>(sbf, Apk);
        stft_gemm_pk<<<dim3(GNWG), dim3(512), 0, stream>>>(Apk, Bws, out);
    } else if (ws_size >= WS_TIER2 && d_ws != nullptr) {
        ushort* sbf = (ushort*)d_ws;
        ushort* Bws = sbf + SIG_ELEMS;
        prep_all<<<dim3(PREP_SIG_BLOCKS + PREP_B_BLOCKS), dim3(256), 0, stream>>>(
            sig, wnd, dcos, dsin, sbf, Bws);
        stft_gemm_bp5<<<dim3(GNWG), dim3(1024), 0, stream>>>(sbf, Bws, out);
    } else {
        stft_gemm_fb<<<dim3(NWG), dim3(256), 0, stream>>>(sig, wnd, dcos, dsin, out);
    }
}

// Round 14
// 61.236 us; speedup vs baseline: 1.0405x; 1.0405x over previous
//
#include <hip/hip_runtime.h>
#include <hip/hip_bf16.h>

// ---- problem constants ----
#define NBATCH   16
#define SIGLEN   240000
#define FRAMES   1197                 // (240000-800)/200 + 1
#define M_TOTAL  (NBATCH * FRAMES)    // 19152 = 1197 * 16 exactly
#define K_TOTAL  800
#define NBINS    401
#define NOUT     (2 * NBINS)          // 802, interleaved re/im
#define FSTEP    200

// ---- GEMM geometry ----
#define KPAD  832                     // K padded to 26*32 (B cols 800..831 zero)
#define NTK   26                      // K-steps of 32
#define GBN   64                      // N cols per block (B panel rows)
#define GMB   1024                    // M rows per block (8 waves x 128)
#define GNT   13                      // ceil(802/64)
#define GMT   19                      // ceil(19152/1024)
#define GNWG  (GNT * GMT)             // 247 blocks -> 1/CU
#define BSTR  840                     // LDS row stride bf16
#define NRG   1197                    // row-groups of 16 (exact)
#define SCSTR 68                      // epilogue LDS f32 stride (16B-aligned rows)

#define SIG_ELEMS  ((size_t)NBATCH * SIGLEN)          // 3,840,000 f32
#define B_WS_ELEMS ((size_t)(GNT * GBN) * KPAD)       // 692,224 bf16
#define APK_ELEMS  ((size_t)NRG * NTK * 64 * 8)       // 15,937,536 bf16 (~31.9MB)
#define WS_TIER1   ((APK_ELEMS + B_WS_ELEMS) * 2)     // ~33.3 MB
#define WS_TIER2   ((SIG_ELEMS + B_WS_ELEMS) * 2)     // ~9.07 MB

#define PREP_B_BLOCKS 338             // 832 rows * 104 chunks / 256
#define PREP_SIG_BLOCKS 1875
#define PACK_TOTAL (NRG * NTK * 64)   // 1,991,808
#define PACK_BLOCKS ((PACK_TOTAL + 255) / 256)

typedef float  f32x4  __attribute__((ext_vector_type(4)));
typedef __bf16 bf16x8 __attribute__((ext_vector_type(8)));

static __device__ __forceinline__ unsigned f2bf_pair(float lo, float hi) {
    union { float f; unsigned u; } a, b;
    a.f = lo; b.f = hi;
    unsigned ua = (a.u + 0x7fffu + ((a.u >> 16) & 1u)) >> 16;
    unsigned ub = (b.u + 0x7fffu + ((b.u >> 16) & 1u)) >> 16;
    return ua | (ub << 16);
}

// ============================================================================
// prep B: windowed interleaved-DFT bf16 rows, K-padded to 832 (tier1)
// ============================================================================
__global__ __launch_bounds__(256) void prep_b(
    const float* __restrict__ dcos, const float* __restrict__ dsin,
    const float* __restrict__ wnd, ushort* __restrict__ B)
{
    int idx = blockIdx.x * 256 + threadIdx.x;   // < 832*104
    int j  = idx / 104;
    int c8 = (idx - j * 104) * 8;
    uint4 p;
    if (j < NOUT && c8 < K_TOTAL) {
        const float* src = ((j & 1) ? dsin : dcos) + (size_t)(j >> 1) * K_TOTAL + c8;
        const float4 s0 = *(const float4*)(src);
        const float4 s1 = *(const float4*)(src + 4);
        const float4 w0 = *(const float4*)(wnd + c8);
        const float4 w1 = *(const float4*)(wnd + c8 + 4);
        p.x = f2bf_pair(s0.x * w0.x, s0.y * w0.y);
        p.y = f2bf_pair(s0.z * w0.z, s0.w * w0.w);
        p.z = f2bf_pair(s1.x * w1.x, s1.y * w1.y);
        p.w = f2bf_pair(s1.z * w1.z, s1.w * w1.w);
    } else {
        p = make_uint4(0u, 0u, 0u, 0u);
    }
    *(uint4*)(B + (size_t)j * KPAD + c8) = p;
}

// ============================================================================
// pack A (reads f32 signal DIRECTLY, converts, writes MFMA fragment order):
// A_pk[(rowgrp*26 + kk)*64 + lane] = 8 bf16; scattered gather happens ONCE.
// Clamp keeps kk=25 tail reads in-bounds (garbage x zero-B-col = 0).
// ============================================================================
__global__ __launch_bounds__(256) void prep_pack(
    const float* __restrict__ sig, ushort* __restrict__ Apk)
{
    int idx = blockIdx.x * 256 + threadIdx.x;
    if (idx >= PACK_TOTAL) return;
    const int lane   = idx & 63;
    const int kk     = (idx >> 6) % NTK;
    const int rowgrp = idx / (64 * NTK);
    const int row = rowgrp * 16 + (lane & 15);
    const int bb  = row / FRAMES, ff = row - bb * FRAMES;
    size_t off = (size_t)bb * SIGLEN + ff * FSTEP + kk * 32 + (lane >> 4) * 8;
    if (off > SIG_ELEMS - 8) off = SIG_ELEMS - 8;
    const float4 s0 = *(const float4*)(sig + off);
    const float4 s1 = *(const float4*)(sig + off + 4);
    uint4 p;
    p.x = f2bf_pair(s0.x, s0.y);
    p.y = f2bf_pair(s0.z, s0.w);
    p.z = f2bf_pair(s1.x, s1.y);
    p.w = f2bf_pair(s1.z, s1.w);
    *(uint4*)(Apk + (size_t)idx * 8) = p;
}

// ============================================================================
// GEMM tier1: R13 K-loop (packed-A, B panel in LDS, 26 steps, no barriers,
// depth-2 ping-pong) + NEW LDS-transposed epilogue: each wave stages its
// C frags through reused B-panel LDS and emits row-contiguous float4 stores
// (4 coalesced 1KB stores per i-frag vs 16 scattered scalar = ~16x fewer
// line-touches -> kills the TA-bound store path identified in R13 PM).
// ============================================================================
__global__ __launch_bounds__(512, 2) void stft_gemm_pk(
    const ushort* __restrict__ Apk, const ushort* __restrict__ Bw,
    float* __restrict__ out)
{
    __shared__ ushort Bs[GBN * BSTR];   // 107,520 B; reused as f32 scratch later

    const int tid  = threadIdx.x;

    // XCD-chunked bijective swizzle (m204): nwg=247, q=30, r=7; ntile fastest.
    const int orig = blockIdx.x;
    const int xcd  = orig & 7;
    const int idx  = orig >> 3;
    const int lbid = (xcd < 7 ? xcd * 31 : 217 + (xcd - 7) * 30) + idx;

    const int ntile = lbid % GNT;
    const int mblk  = lbid / GNT;
    const int j0    = ntile * GBN;
    const int m0    = mblk * GMB;

    const int wave = tid >> 6;
    const int lane = tid & 63;
    const int lr   = lane & 15;
    const int lg   = lane >> 4;
    const int mrow = m0 + wave * 128;

    // per-i-frag packed row-group bases (elems); fits 32-bit
    const int g0 = (m0 >> 4) + wave * 8;
    unsigned aBase[8];
    #pragma unroll
    for (int i = 0; i < 8; ++i) {
        int g = g0 + i;
        if (g >= NRG) g = NRG - 1;      // tail mblk: dup rowgrp, never stored
        aBase[i] = (unsigned)g * (NTK * 512) + lane * 8;
    }

    f32x4 acc[8][4];
    #pragma unroll
    for (int i = 0; i < 8; ++i)
        #pragma unroll
        for (int jj = 0; jj < 4; ++jj)
            acc[i][jj] = (f32x4){0.f, 0.f, 0.f, 0.f};

#define LOADA(A_, step) do {                                        \
        _Pragma("unroll")                                           \
        for (int i = 0; i < 8; ++i)                                 \
            A_[i] = *(const bf16x8*)(Apk + (size_t)aBase[i] + (step) * 512); \
    } while (0)

#define LOADB(B_, step) do {                                        \
        const int kofs_ = (step) * 32;                              \
        _Pragma("unroll")                                           \
        for (int jj = 0; jj < 4; ++jj)                              \
            B_[jj] = *(const bf16x8*)&Bs[jj * (16 * BSTR) + lr * BSTR + lg * 8 + kofs_]; \
    } while (0)

#define MM(A_, B_) do {                                             \
        __builtin_amdgcn_s_setprio(1);                              \
        _Pragma("unroll")                                           \
        for (int i = 0; i < 8; ++i)                                 \
            _Pragma("unroll")                                       \
            for (int jj = 0; jj < 4; ++jj)                          \
                acc[i][jj] = __builtin_amdgcn_mfma_f32_16x16x32_bf16( \
                    A_[i], B_[jj], acc[i][jj], 0, 0, 0);            \
        __builtin_amdgcn_s_setprio(0);                              \
    } while (0)

    bf16x8 aX[8], aY[8], bX[4], bY[4];

    LOADA(aX, 0);
    LOADA(aY, 1);

    // ---- stage B panel: 64 rows x 832 cols -> LDS [64][840] ----
    #pragma unroll
    for (int it = 0; it < 13; ++it) {
        int c   = tid + 512 * it;
        int row = c / 104;
        int col = (c - row * 104) * 8;
        *(uint4*)&Bs[row * BSTR + col] =
            *(const uint4*)(Bw + (size_t)(j0 + row) * KPAD + col);
    }
    __syncthreads();

    LOADB(bX, 0);
    LOADB(bY, 1);

    #pragma unroll 1
    for (int t = 0; t < NTK - 2; t += 2) {
        MM(aX, bX);
        LOADA(aX, t + 2);
        LOADB(bX, t + 2);
        MM(aY, bY);
        LOADA(aY, t + 3);
        LOADB(bY, t + 3);
    }
    MM(aX, bX);   // step 24
    MM(aY, bY);   // step 25

#undef LOADA
#undef LOADB
#undef MM

    // ---- epilogue: LDS-transposed coalesced C stores ----
    __syncthreads();   // all waves done reading B panel before reuse as scratch
    float* sc = (float*)Bs + wave * (16 * SCSTR);   // 4352B/wave, 34.8KB total
    const int rl = lane >> 2;        // output row within 16-row frag
    const int kq = lane & 3;         // 16B chunk within 64B row segment

    #pragma unroll
    for (int i = 0; i < 8; ++i) {
        __builtin_amdgcn_sched_barrier(0);
        // scatter frag i into per-wave LDS tile [16][SCSTR]
        #pragma unroll
        for (int jj = 0; jj < 4; ++jj)
            #pragma unroll
            for (int r = 0; r < 4; ++r)
                sc[(lg * 4 + r) * SCSTR + jj * 16 + lr] = acc[i][jj][r];
        asm volatile("s_waitcnt lgkmcnt(0)" ::: "memory");
        __builtin_amdgcn_sched_barrier(0);
        // gather row-contiguous and store coalesced
        int row = mrow + i * 16 + rl;
        if (row < M_TOTAL) {
            float* op = out + (size_t)row * NOUT;
            #pragma unroll
            for (int ch = 0; ch < 4; ++ch) {
                int colb = j0 + ch * 16 + kq * 4;
                float4 v = *(float4*)&sc[rl * SCSTR + ch * 16 + kq * 4];
                if (colb + 3 < NOUT) {
                    *(float4*)(op + colb) = v;
                } else {
                    #pragma unroll
                    for (int e = 0; e < 4; ++e)
                        if (colb + e < NOUT) op[colb + e] = ((float*)&v)[e];
                }
            }
        }
        asm volatile("s_waitcnt lgkmcnt(0)" ::: "memory");   // WAR before next i
        __builtin_amdgcn_sched_barrier(0);
    }
}

// ============================================================================
// tier2 prep: signal f32->bf16 + B (legacy fused prep for bp5 path)
// ============================================================================
__global__ __launch_bounds__(256) void prep_all(
    const float* __restrict__ sig, const float* __restrict__ wnd,
    const float* __restrict__ dcos, const float* __restrict__ dsin,
    ushort* __restrict__ sbf, ushort* __restrict__ B)
{
    const int blk = blockIdx.x;
    if (blk < PREP_SIG_BLOCKS) {
        size_t i8 = ((size_t)blk * 256 + threadIdx.x) * 8;
        const float4 s0 = *(const float4*)(sig + i8);
        const float4 s1 = *(const float4*)(sig + i8 + 4);
        uint4 p;
        p.x = f2bf_pair(s0.x, s0.y);
        p.y = f2bf_pair(s0.z, s0.w);
        p.z = f2bf_pair(s1.x, s1.y);
        p.w = f2bf_pair(s1.z, s1.w);
        *(uint4*)(sbf + i8) = p;
    } else {
        int idx = (blk - PREP_SIG_BLOCKS) * 256 + threadIdx.x;
        int j  = idx / 104;
        int c8 = (idx - j * 104) * 8;
        uint4 p;
        if (j < NOUT && c8 < K_TOTAL) {
            const float* src = ((j & 1) ? dsin : dcos) + (size_t)(j >> 1) * K_TOTAL + c8;
            const float4 s0 = *(const float4*)(src);
            const float4 s1 = *(const float4*)(src + 4);
            const float4 w0 = *(const float4*)(wnd + c8);
            const float4 w1 = *(const float4*)(wnd + c8 + 4);
            p.x = f2bf_pair(s0.x * w0.x, s0.y * w0.y);
            p.y = f2bf_pair(s0.z * w0.z, s0.w * w0.w);
            p.z = f2bf_pair(s1.x * w1.x, s1.y * w1.y);
            p.w = f2bf_pair(s1.z * w1.z, s1.w * w1.w);
        } else {
            p = make_uint4(0u, 0u, 0u, 0u);
        }
        *(uint4*)(B + (size_t)j * KPAD + c8) = p;
    }
}

// ============================================================================
// GEMM tier2 (R12 kernel): direct-signal A, 16 waves x 64x64
// ============================================================================
__global__ __launch_bounds__(1024, 4) void stft_gemm_bp5(
    const ushort* __restrict__ sigbf, const ushort* __restrict__ Bw,
    float* __restrict__ out)
{
    __shared__ ushort Bs[GBN * BSTR];

    const int tid  = threadIdx.x;
    const int orig = blockIdx.x;
    const int xcd  = orig & 7;
    const int idx  = orig >> 3;
    const int lbid = (xcd < 7 ? xcd * 31 : 217 + (xcd - 7) * 30) + idx;

    const int ntile = lbid % GNT;
    const int mblk  = lbid / GNT;
    const int j0    = ntile * GBN;
    const int m0    = mblk * GMB;

    const int wave = tid >> 6;
    const int lane = tid & 63;
    const int lr   = lane & 15;
    const int lg   = lane >> 4;
    const int mrow = m0 + wave * 64;

    unsigned aOfs[4];
    #pragma unroll
    for (int i = 0; i < 4; ++i) {
        int row = mrow + i * 16 + lr;
        if (row >= M_TOTAL) row = M_TOTAL - 1;
        int bb = row / FRAMES, ff = row - bb * FRAMES;
        aOfs[i] = (unsigned)(bb * SIGLEN + ff * FSTEP + lg * 8);
    }
    const int bBase = lr * BSTR + lg * 8;

    f32x4 acc[4][4];
    #pragma unroll
    for (int i = 0; i < 4; ++i)
        #pragma unroll
        for (int jj = 0; jj < 4; ++jj)
            acc[i][jj] = (f32x4){0.f, 0.f, 0.f, 0.f};

#define LOADA(A_, step) do {                                        \
        const int kofs_ = (step) * 32;                              \
        _Pragma("unroll")                                           \
        for (int i = 0; i < 4; ++i)                                 \
            A_[i] = *(const bf16x8*)(sigbf + aOfs[i] + kofs_);      \
    } while (0)

#define LOADB(B_, step) do {                                        \
        const int kofs_ = (step) * 32;                              \
        _Pragma("unroll")                                           \
        for (int jj = 0; jj < 4; ++jj)                              \
            B_[jj] = *(const bf16x8*)&Bs[jj * (16 * BSTR) + bBase + kofs_]; \
    } while (0)

#define MM(A_, B_) do {                                             \
        __builtin_amdgcn_s_setprio(1);                              \
        _Pragma("unroll")                                           \
        for (int i = 0; i < 4; ++i)                                 \
            _Pragma("unroll")                                       \
            for (int jj = 0; jj < 4; ++jj)                          \
                acc[i][jj] = __builtin_amdgcn_mfma_f32_16x16x32_bf16( \
                    A_[i], B_[jj], acc[i][jj], 0, 0, 0);            \
        __builtin_amdgcn_s_setprio(0);                              \
    } while (0)

    bf16x8 aX[4], aY[4], bX[4];

    LOADA(aX, 0);
    LOADA(aY, 1);

    #pragma unroll
    for (int it = 0; it < 6; ++it) {
        int c   = tid + 1024 * it;
        int row = c / 104;
        int col = (c - row * 104) * 8;
        *(uint4*)&Bs[row * BSTR + col] =
            *(const uint4*)(Bw + (size_t)(j0 + row) * KPAD + col);
    }
    if (tid < 512) {
        int c   = tid + 6144;
        int row = c / 104;
        int col = (c - row * 104) * 8;
        *(uint4*)&Bs[row * BSTR + col] =
            *(const uint4*)(Bw + (size_t)(j0 + row) * KPAD + col);
    }
    __syncthreads();

    #pragma unroll 1
    for (int t = 0; t < NTK - 2; t += 2) {
        LOADB(bX, t);
        MM(aX, bX);
        LOADA(aX, t + 2);
        LOADB(bX, t + 1);
        MM(aY, bX);
        LOADA(aY, t + 3);
    }
    LOADB(bX, 24); MM(aX, bX);
    LOADB(bX, 25); MM(aY, bX);

#undef LOADA
#undef LOADB
#undef MM

    #pragma unroll
    for (int i = 0; i < 4; ++i) {
        #pragma unroll
        for (int jj = 0; jj < 4; ++jj) {
            int col = j0 + jj * 16 + lr;
            if (col >= NOUT) continue;
            #pragma unroll
            for (int r = 0; r < 4; ++r) {
                int row = mrow + i * 16 + lg * 4 + r;
                if (row < M_TOTAL)
                    out[(size_t)row * NOUT + col] = acc[i][jj][r];
            }
        }
    }
}

// ============================================================================
// fallback (no workspace): in-kernel gather+window+convert
// ============================================================================
#define BM 128
#define BN 128
#define BK 32
#define NTILES_N 7
#define NTILES_M 150
#define NWG (NTILES_M * NTILES_N)
#define LDSS 40
__global__ __launch_bounds__(256) void stft_gemm_fb(
    const float* __restrict__ sig, const float* __restrict__ wnd,
    const float* __restrict__ dcos, const float* __restrict__ dsin,
    float* __restrict__ out)
{
    __shared__ ushort As[BM * LDSS];
    __shared__ ushort Bs[BN * LDSS];
    __shared__ int rowBase[BM];

    const int tid = threadIdx.x;
    const int bid = blockIdx.x;
    const int mt  = bid / NTILES_N;
    const int nt  = bid - mt * NTILES_N;
    const int m0  = mt * BM;
    const int j0  = nt * BN;

    if (tid < BM) {
        int m = m0 + tid;
        int v = -1;
        if (m < M_TOTAL) {
            int b  = m / FRAMES;
            int fl = m - b * FRAMES;
            v = b * SIGLEN + fl * FSTEP;
        }
        rowBase[tid] = v;
    }

    const int rS = tid >> 1;
    const int hS = tid & 1;

    const float* bRow = nullptr;
    {
        int j = j0 + rS;
        if (j < NOUT) {
            const float* srcm = (j & 1) ? dsin : dcos;
            bRow = srcm + (size_t)(j >> 1) * K_TOTAL;
        }
    }

    const int lane = tid & 63;
    const int wave = tid >> 6;
    const int wm   = wave >> 1;
    const int wn   = wave & 1;
    const int lr   = lane & 15;
    const int lg   = lane >> 4;

    f32x4 acc[4][4];
    #pragma unroll
    for (int i = 0; i < 4; ++i)
        #pragma unroll
        for (int jj = 0; jj < 4; ++jj)
            acc[i][jj] = (f32x4){0.f, 0.f, 0.f, 0.f};

    __syncthreads();

    for (int k0 = 0; k0 < K_TOTAL; k0 += BK) {
        {
            int base = rowBase[rS];
            float4 f0, f1, f2, f3;
            if (base >= 0) {
                const float4* sp = (const float4*)(sig + base + k0 + hS * 16);
                f0 = sp[0]; f1 = sp[1]; f2 = sp[2]; f3 = sp[3];
            } else {
                f0 = make_float4(0.f,0.f,0.f,0.f); f1 = f0; f2 = f0; f3 = f0;
            }
            const float4* wp = (const float4*)(wnd + k0 + hS * 16);
            float4 w0 = wp[0], w1 = wp[1], w2 = wp[2], w3 = wp[3];
            uint4 p0, p1;
            p0.x = f2bf_pair(f0.x * w0.x, f0.y * w0.y);
            p0.y = f2bf_pair(f0.z * w0.z, f0.w * w0.w);
            p0.z = f2bf_pair(f1.x * w1.x, f1.y * w1.y);
            p0.w = f2bf_pair(f1.z * w1.z, f1.w * w1.w);
            p1.x = f2bf_pair(f2.x * w2.x, f2.y * w2.y);
            p1.y = f2bf_pair(f2.z * w2.z, f2.w * w2.w);
            p1.z = f2bf_pair(f3.x * w3.x, f3.y * w3.y);
            p1.w = f2bf_pair(f3.z * w3.z, f3.w * w3.w);
            uint4* dst = (uint4*)&As[rS * LDSS + hS * 16];
            dst[0] = p0; dst[1] = p1;
        }
        {
            uint4 p0, p1;
            if (bRow) {
                const float4* sp = (const float4*)(bRow + k0 + hS * 16);
                float4 f0 = sp[0], f1 = sp[1], f2 = sp[2], f3 = sp[3];
                p0.x = f2bf_pair(f0.x, f0.y);
                p0.y = f2bf_pair(f0.z, f0.w);
                p0.z = f2bf_pair(f1.x, f1.y);
                p0.w = f2bf_pair(f1.z, f1.w);
                p1.x = f2bf_pair(f2.x, f2.y);
                p1.y = f2bf_pair(f2.z, f2.w);
                p1.z = f2bf_pair(f3.x, f3.y);
                p1.w = f2bf_pair(f3.z, f3.w);
            } else {
                p0 = make_uint4(0u,0u,0u,0u); p1 = p0;
            }
            uint4* dst = (uint4*)&Bs[rS * LDSS + hS * 16];
            dst[0] = p0; dst[1] = p1;
        }
        __syncthreads();

        bf16x8 a[4], b[4];
        #pragma unroll
        for (int i = 0; i < 4; ++i)
            a[i] = *(const bf16x8*)&As[(wm * 64 + i * 16 + lr) * LDSS + lg * 8];
        #pragma unroll
        for (int i = 0; i < 4; ++i)
            b[i] = *(const bf16x8*)&Bs[(wn * 64 + i * 16 + lr) * LDSS + lg * 8];
        #pragma unroll
        for (int i = 0; i < 4; ++i)
            #pragma unroll
            for (int jj = 0; jj < 4; ++jj)
                acc[i][jj] = __builtin_amdgcn_mfma_f32_16x16x32_bf16(a[i], b[jj], acc[i][jj], 0, 0, 0);

        __syncthreads();
    }

    const int mb = m0 + wm * 64;
    const int jb = j0 + wn * 64;
    #pragma unroll
    for (int i = 0; i < 4; ++i) {
        #pragma unroll
        for (int jj = 0; jj < 4; ++jj) {
            int col = jb + jj * 16 + lr;
            if (col >= NOUT) continue;
            #pragma unroll
            for (int r = 0; r < 4; ++r) {
                int row = mb + i * 16 + lg * 4 + r;
                if (row < M_TOTAL)
                    out[(size_t)row * NOUT + col] = acc[i][jj][r];
            }
        }
    }
}

extern "C" void kernel_launch(void* const* d_in, const int* in_sizes, int n_in,
                              void* d_out, int out_size, void* d_ws, size_t ws_size,
                              hipStream_t stream) {
    const float* sig  = (const float*)d_in[0];
    const float* wnd  = (const float*)d_in[1];
    const float* dcos = (const float*)d_in[2];
    const float* dsin = (const float*)d_in[3];
    float* out = (float*)d_out;

    if (ws_size >= WS_TIER1 && d_ws != nullptr) {
        ushort* Apk = (ushort*)d_ws;
        ushort* Bws = Apk + APK_ELEMS;
        prep_b<<<dim3(PREP_B_BLOCKS), dim3(256), 0, stream>>>(dcos, dsin, wnd, Bws);
        prep_pack<<<dim3(PACK_BLOCKS), dim3(256), 0, stream>>>(sig, Apk);
        stft_gemm_pk<<<dim3(GNWG), dim3(512), 0, stream>>>(Apk, Bws, out);
    } else if (ws_size >= WS_TIER2 && d_ws != nullptr) {
        ushort* sbf = (ushort*)d_ws;
        ushort* Bws = sbf + SIG_ELEMS;
        prep_all<<<dim3(PREP_SIG_BLOCKS + PREP_B_BLOCKS), dim3(256), 0, stream>>>(
            sig, wnd, dcos, dsin, sbf, Bws);
        stft_gemm_bp5<<<dim3(GNWG), dim3(1024), 0, stream>>>(sbf, Bws, out);
    } else {
        stft_gemm_fb<<<dim3(NWG), dim3(256), 0, stream>>>(sig, wnd, dcos, dsin, out);
    }
}